// Round 9
// baseline (1736.693 us; speedup 1.0000x reference)
//
#include <hip/hip_runtime.h>

// VectorQuantizer: z (8,64,8192) f32, codebook (1024,64) f32
// Outputs (concatenated f32): z_q_st [4194304], vq_loss [1], codes [65536]
//
// codes must match numpy fp32 argmin BIT-EXACTLY -> replicate numpy op order:
//   zsq/wsq: pairwise_sum n=64 (8 serial column accumulators, rounded squares)
//   dot:     single serial FMA chain over k ascending (BLAS sgemm order)
//   dist:    fl(fl(zsq - fl(2*dot)) + wsq), argmin = first occurrence of min.
//
// Evidence ledger:
//   R6-R9: row-per-thread, w via s_load: 190us invariant (SMEM/DS lgkmcnt OOO
//     full-drains). R11: w per-lane VMEM: 500us (64x L1 amplification).
//   R12: transpose (lanes own 2 codes, w in regs ONCE, z broadcast LDS):
//     209us. R13: batch 4 rows/iter (pipelined shfl chains): 175us,
//     VALUBusy 56.6%. Gap analysis: 3281cy/iter-slot vs 1224cy issue ->
//     ~600cy/iter residual == the 6 dependent shfl levels STILL serialized
//     at the END of each iteration body; widening can't shrink a chain that
//     never overlaps FMAs within one wave (only 2 waves/SIMD to cover).
// R14 (this round): SOFTWARE-PIPELINE the reduction one iteration back.
//   Body = {FMA block for iter i} then {reduction for iter i-1}: the shfl
//   chain now overlaps 512 independent FMA issue slots in the same
//   scheduling window. Carried: 4 premin d + 4 tB (8 regs). FP order per
//   (row,code) untouched -> bit-exact.
//   Predict: dist 175 -> 110-140us; total -> 175-205; VALUBusy 65-80%.
//   Falsifier: unchanged -> overlap failed (or tail isn't shfl) -> next:
//   split-tile staging (32KB halves -> 4 blocks/CU, hide tail with TLP).

#define T_DIM 8192
#define D_DIM 64
#define C_DIM 1024
#define B_DIM 8
#define NROWS (B_DIM * T_DIM)           // 65536 vectors
#define NELEM (B_DIM * D_DIM * T_DIM)   // 4194304 elements
#define SEGS 2                          // blockIdx.y segments (512 codes each)
#define EPI_BLOCKS (NELEM / 4 / 256)    // 4096 blocks, 1 float4/thread

#define R64(M) M(0) M(1) M(2) M(3) M(4) M(5) M(6) M(7) \
  M(8) M(9) M(10) M(11) M(12) M(13) M(14) M(15) \
  M(16) M(17) M(18) M(19) M(20) M(21) M(22) M(23) \
  M(24) M(25) M(26) M(27) M(28) M(29) M(30) M(31) \
  M(32) M(33) M(34) M(35) M(36) M(37) M(38) M(39) \
  M(40) M(41) M(42) M(43) M(44) M(45) M(46) M(47) \
  M(48) M(49) M(50) M(51) M(52) M(53) M(54) M(55) \
  M(56) M(57) M(58) M(59) M(60) M(61) M(62) M(63)

#define SQ_(x) __fmul_rn(x, x)
#define AD_(a, b) __fadd_rn(a, b)

// numpy pairwise_sum of 64 pre-rounded squares of scalars p0..p63 -> dst.
#define PAIRWISE64(p, dst) \
  float pr0 = SQ_(p##0);  pr0 = AD_(pr0, SQ_(p##8));  pr0 = AD_(pr0, SQ_(p##16)); pr0 = AD_(pr0, SQ_(p##24)); pr0 = AD_(pr0, SQ_(p##32)); pr0 = AD_(pr0, SQ_(p##40)); pr0 = AD_(pr0, SQ_(p##48)); pr0 = AD_(pr0, SQ_(p##56)); \
  float pr1 = SQ_(p##1);  pr1 = AD_(pr1, SQ_(p##9));  pr1 = AD_(pr1, SQ_(p##17)); pr1 = AD_(pr1, SQ_(p##25)); pr1 = AD_(pr1, SQ_(p##33)); pr1 = AD_(pr1, SQ_(p##41)); pr1 = AD_(pr1, SQ_(p##49)); pr1 = AD_(pr1, SQ_(p##57)); \
  float pr2 = SQ_(p##2);  pr2 = AD_(pr2, SQ_(p##10)); pr2 = AD_(pr2, SQ_(p##18)); pr2 = AD_(pr2, SQ_(p##26)); pr2 = AD_(pr2, SQ_(p##34)); pr2 = AD_(pr2, SQ_(p##42)); pr2 = AD_(pr2, SQ_(p##50)); pr2 = AD_(pr2, SQ_(p##58)); \
  float pr3 = SQ_(p##3);  pr3 = AD_(pr3, SQ_(p##11)); pr3 = AD_(pr3, SQ_(p##19)); pr3 = AD_(pr3, SQ_(p##27)); pr3 = AD_(pr3, SQ_(p##35)); pr3 = AD_(pr3, SQ_(p##43)); pr3 = AD_(pr3, SQ_(p##51)); pr3 = AD_(pr3, SQ_(p##59)); \
  float pr4 = SQ_(p##4);  pr4 = AD_(pr4, SQ_(p##12)); pr4 = AD_(pr4, SQ_(p##20)); pr4 = AD_(pr4, SQ_(p##28)); pr4 = AD_(pr4, SQ_(p##36)); pr4 = AD_(pr4, SQ_(p##44)); pr4 = AD_(pr4, SQ_(p##52)); pr4 = AD_(pr4, SQ_(p##60)); \
  float pr5 = SQ_(p##5);  pr5 = AD_(pr5, SQ_(p##13)); pr5 = AD_(pr5, SQ_(p##21)); pr5 = AD_(pr5, SQ_(p##29)); pr5 = AD_(pr5, SQ_(p##37)); pr5 = AD_(pr5, SQ_(p##45)); pr5 = AD_(pr5, SQ_(p##53)); pr5 = AD_(pr5, SQ_(p##61)); \
  float pr6 = SQ_(p##6);  pr6 = AD_(pr6, SQ_(p##14)); pr6 = AD_(pr6, SQ_(p##22)); pr6 = AD_(pr6, SQ_(p##30)); pr6 = AD_(pr6, SQ_(p##38)); pr6 = AD_(pr6, SQ_(p##46)); pr6 = AD_(pr6, SQ_(p##54)); pr6 = AD_(pr6, SQ_(p##62)); \
  float pr7 = SQ_(p##7);  pr7 = AD_(pr7, SQ_(p##15)); pr7 = AD_(pr7, SQ_(p##23)); pr7 = AD_(pr7, SQ_(p##31)); pr7 = AD_(pr7, SQ_(p##39)); pr7 = AD_(pr7, SQ_(p##47)); pr7 = AD_(pr7, SQ_(p##55)); pr7 = AD_(pr7, SQ_(p##63)); \
  float dst = AD_(AD_(AD_(pr0, pr1), AD_(pr2, pr3)), AD_(AD_(pr4, pr5), AD_(pr6, pr7)));

// Same pairwise order, sourced from a float4[16] register array.
#define WSQ_OF(arr, dst) float dst; { \
  float c0 = SQ_(arr[0].x); c0=AD_(c0,SQ_(arr[2].x)); c0=AD_(c0,SQ_(arr[4].x)); c0=AD_(c0,SQ_(arr[6].x)); c0=AD_(c0,SQ_(arr[8].x)); c0=AD_(c0,SQ_(arr[10].x)); c0=AD_(c0,SQ_(arr[12].x)); c0=AD_(c0,SQ_(arr[14].x)); \
  float c1 = SQ_(arr[0].y); c1=AD_(c1,SQ_(arr[2].y)); c1=AD_(c1,SQ_(arr[4].y)); c1=AD_(c1,SQ_(arr[6].y)); c1=AD_(c1,SQ_(arr[8].y)); c1=AD_(c1,SQ_(arr[10].y)); c1=AD_(c1,SQ_(arr[12].y)); c1=AD_(c1,SQ_(arr[14].y)); \
  float c2 = SQ_(arr[0].z); c2=AD_(c2,SQ_(arr[2].z)); c2=AD_(c2,SQ_(arr[4].z)); c2=AD_(c2,SQ_(arr[6].z)); c2=AD_(c2,SQ_(arr[8].z)); c2=AD_(c2,SQ_(arr[10].z)); c2=AD_(c2,SQ_(arr[12].z)); c2=AD_(c2,SQ_(arr[14].z)); \
  float c3 = SQ_(arr[0].w); c3=AD_(c3,SQ_(arr[2].w)); c3=AD_(c3,SQ_(arr[4].w)); c3=AD_(c3,SQ_(arr[6].w)); c3=AD_(c3,SQ_(arr[8].w)); c3=AD_(c3,SQ_(arr[10].w)); c3=AD_(c3,SQ_(arr[12].w)); c3=AD_(c3,SQ_(arr[14].w)); \
  float c4 = SQ_(arr[1].x); c4=AD_(c4,SQ_(arr[3].x)); c4=AD_(c4,SQ_(arr[5].x)); c4=AD_(c4,SQ_(arr[7].x)); c4=AD_(c4,SQ_(arr[9].x)); c4=AD_(c4,SQ_(arr[11].x)); c4=AD_(c4,SQ_(arr[13].x)); c4=AD_(c4,SQ_(arr[15].x)); \
  float c5 = SQ_(arr[1].y); c5=AD_(c5,SQ_(arr[3].y)); c5=AD_(c5,SQ_(arr[5].y)); c5=AD_(c5,SQ_(arr[7].y)); c5=AD_(c5,SQ_(arr[9].y)); c5=AD_(c5,SQ_(arr[11].y)); c5=AD_(c5,SQ_(arr[13].y)); c5=AD_(c5,SQ_(arr[15].y)); \
  float c6 = SQ_(arr[1].z); c6=AD_(c6,SQ_(arr[3].z)); c6=AD_(c6,SQ_(arr[5].z)); c6=AD_(c6,SQ_(arr[7].z)); c6=AD_(c6,SQ_(arr[9].z)); c6=AD_(c6,SQ_(arr[11].z)); c6=AD_(c6,SQ_(arr[13].z)); c6=AD_(c6,SQ_(arr[15].z)); \
  float c7 = SQ_(arr[1].w); c7=AD_(c7,SQ_(arr[3].w)); c7=AD_(c7,SQ_(arr[5].w)); c7=AD_(c7,SQ_(arr[7].w)); c7=AD_(c7,SQ_(arr[9].w)); c7=AD_(c7,SQ_(arr[11].w)); c7=AD_(c7,SQ_(arr[13].w)); c7=AD_(c7,SQ_(arr[15].w)); \
  dst = AD_(AD_(AD_(c0, c1), AD_(c2, c3)), AD_(AD_(c4, c5), AD_(c6, c7))); }

// FMA block for rows R..R+3: 8 serial chains (k ascending per (row,code)),
// dist, pair pre-min (A wins ties). Outputs premin'd d and tookB flags.
#define FMA4BLOCK(R, dO0, dO1, dO2, dO3, tO0, tO1, tO2, tO3) { \
    float aA0 = 0.f, aA1 = 0.f, aA2 = 0.f, aA3 = 0.f; \
    float aB0 = 0.f, aB1 = 0.f, aB2 = 0.f, aB3 = 0.f; \
    _Pragma("unroll") \
    for (int kk = 0; kk < 16; ++kk) { \
        const float4 zc0 = zl[kk][(R) + 0]; \
        const float4 zc1 = zl[kk][(R) + 1]; \
        const float4 zc2 = zl[kk][(R) + 2]; \
        const float4 zc3 = zl[kk][(R) + 3]; \
        const float4 WA = wa[kk]; \
        const float4 WB = wb[kk]; \
        aA0 = fmaf(zc0.x, WA.x, aA0); aA0 = fmaf(zc0.y, WA.y, aA0); \
        aA0 = fmaf(zc0.z, WA.z, aA0); aA0 = fmaf(zc0.w, WA.w, aA0); \
        aB0 = fmaf(zc0.x, WB.x, aB0); aB0 = fmaf(zc0.y, WB.y, aB0); \
        aB0 = fmaf(zc0.z, WB.z, aB0); aB0 = fmaf(zc0.w, WB.w, aB0); \
        aA1 = fmaf(zc1.x, WA.x, aA1); aA1 = fmaf(zc1.y, WA.y, aA1); \
        aA1 = fmaf(zc1.z, WA.z, aA1); aA1 = fmaf(zc1.w, WA.w, aA1); \
        aB1 = fmaf(zc1.x, WB.x, aB1); aB1 = fmaf(zc1.y, WB.y, aB1); \
        aB1 = fmaf(zc1.z, WB.z, aB1); aB1 = fmaf(zc1.w, WB.w, aB1); \
        aA2 = fmaf(zc2.x, WA.x, aA2); aA2 = fmaf(zc2.y, WA.y, aA2); \
        aA2 = fmaf(zc2.z, WA.z, aA2); aA2 = fmaf(zc2.w, WA.w, aA2); \
        aB2 = fmaf(zc2.x, WB.x, aB2); aB2 = fmaf(zc2.y, WB.y, aB2); \
        aB2 = fmaf(zc2.z, WB.z, aB2); aB2 = fmaf(zc2.w, WB.w, aB2); \
        aA3 = fmaf(zc3.x, WA.x, aA3); aA3 = fmaf(zc3.y, WA.y, aA3); \
        aA3 = fmaf(zc3.z, WA.z, aA3); aA3 = fmaf(zc3.w, WA.w, aA3); \
        aB3 = fmaf(zc3.x, WB.x, aB3); aB3 = fmaf(zc3.y, WB.y, aB3); \
        aB3 = fmaf(zc3.z, WB.z, aB3); aB3 = fmaf(zc3.w, WB.w, aB3); \
    } \
    const float zr0 = zsql[(R) + 0]; \
    const float zr1 = zsql[(R) + 1]; \
    const float zr2 = zsql[(R) + 2]; \
    const float zr3 = zsql[(R) + 3]; \
    const float dA0 = __fadd_rn(__fsub_rn(zr0, __fmul_rn(2.0f, aA0)), wsqA); \
    const float dB0 = __fadd_rn(__fsub_rn(zr0, __fmul_rn(2.0f, aB0)), wsqB); \
    const float dA1 = __fadd_rn(__fsub_rn(zr1, __fmul_rn(2.0f, aA1)), wsqA); \
    const float dB1 = __fadd_rn(__fsub_rn(zr1, __fmul_rn(2.0f, aB1)), wsqB); \
    const float dA2 = __fadd_rn(__fsub_rn(zr2, __fmul_rn(2.0f, aA2)), wsqA); \
    const float dB2 = __fadd_rn(__fsub_rn(zr2, __fmul_rn(2.0f, aB2)), wsqB); \
    const float dA3 = __fadd_rn(__fsub_rn(zr3, __fmul_rn(2.0f, aA3)), wsqA); \
    const float dB3 = __fadd_rn(__fsub_rn(zr3, __fmul_rn(2.0f, aB3)), wsqB); \
    tO0 = (dB0 < dA0); dO0 = tO0 ? dB0 : dA0; \
    tO1 = (dB1 < dA1); dO1 = tO1 ? dB1 : dA1; \
    tO2 = (dB2 < dA2); dO2 = tO2 ? dB2 : dA2; \
    tO3 = (dB3 < dA3); dO3 = tO3 ? dB3 : dA3; }

// Wave argmin for rows RB..RB+3 given premin'd d/tB: 4 interleaved shfl-min
// chains + per-row class ballots (A-class codes < B-class codes; lane order
// = code order within a class -> first-min semantics).
#define REDUCE4(RB, dI0, dI1, dI2, dI3, tI0, tI1, tI2, tI3) { \
    float m0 = dI0, m1 = dI1, m2 = dI2, m3 = dI3; \
    _Pragma("unroll") \
    for (int off = 32; off > 0; off >>= 1) { \
        m0 = fminf(m0, __shfl_xor(m0, off, 64)); \
        m1 = fminf(m1, __shfl_xor(m1, off, 64)); \
        m2 = fminf(m2, __shfl_xor(m2, off, 64)); \
        m3 = fminf(m3, __shfl_xor(m3, off, 64)); \
    } \
    { const unsigned long long mskA = __ballot((!tI0) && (dI0 == m0)); \
      const unsigned long long mskB = __ballot(tI0 && (dI0 == m0)); \
      int code; \
      if (mskA) code = cbase + (__ffsll((long long)mskA) - 1); \
      else      code = cbase + 64 + (__ffsll((long long)mskB) - 1); \
      if (lane == 0) res[wid][(RB) + 0] = make_float2(m0, (float)code); } \
    { const unsigned long long mskA = __ballot((!tI1) && (dI1 == m1)); \
      const unsigned long long mskB = __ballot(tI1 && (dI1 == m1)); \
      int code; \
      if (mskA) code = cbase + (__ffsll((long long)mskA) - 1); \
      else      code = cbase + 64 + (__ffsll((long long)mskB) - 1); \
      if (lane == 0) res[wid][(RB) + 1] = make_float2(m1, (float)code); } \
    { const unsigned long long mskA = __ballot((!tI2) && (dI2 == m2)); \
      const unsigned long long mskB = __ballot(tI2 && (dI2 == m2)); \
      int code; \
      if (mskA) code = cbase + (__ffsll((long long)mskA) - 1); \
      else      code = cbase + 64 + (__ffsll((long long)mskB) - 1); \
      if (lane == 0) res[wid][(RB) + 2] = make_float2(m2, (float)code); } \
    { const unsigned long long mskA = __ballot((!tI3) && (dI3 == m3)); \
      const unsigned long long mskB = __ballot(tI3 && (dI3 == m3)); \
      int code; \
      if (mskA) code = cbase + (__ffsll((long long)mskA) - 1); \
      else      code = cbase + 64 + (__ffsll((long long)mskB) - 1); \
      if (lane == 0) res[wid][(RB) + 3] = make_float2(m3, (float)code); } }

// Transpose layout (R12/R13) + one-deep software pipeline (R14): body =
// {FMA for iter i} then {reduction for iter i-1} so the shfl chain hides
// under 512 independent FMA issue slots.
__global__ __launch_bounds__(256, 2)
void vq_dist_kernel(const float* __restrict__ z,
                    const float* __restrict__ cb,
                    float2* __restrict__ pairs) {
    const int tid  = threadIdx.x;
    const int wid  = tid >> 6;                        // 0..3
    const int lane = tid & 63;
    const int seg  = blockIdx.y;                      // 0..1
    const int row0 = blockIdx.x * 256;                // tile base (same b)
    const int b    = row0 >> 13;                      // 8192 % 256 == 0
    const int t0   = row0 & (T_DIM - 1);

    __shared__ float4 zl[16][256];                    // 64 KiB  [kchunk][row]
    __shared__ float  zsql[256];                      // 1 KiB
    __shared__ float2 res[4][256];                    // 8 KiB   [wave][row]

    // --- stage z tile: thread handles row row0+tid (coalesced d-strided) ---
    {
        const float* zp = z + (size_t)b * (D_DIM * T_DIM) + (t0 + tid);
#define LOADZ(k) float z##k = zp[(size_t)k * T_DIM];
        R64(LOADZ)
#undef LOADZ
        PAIRWISE64(z, zsq)
        zsql[tid] = zsq;
        zl[ 0][tid] = make_float4(z0,  z1,  z2,  z3);
        zl[ 1][tid] = make_float4(z4,  z5,  z6,  z7);
        zl[ 2][tid] = make_float4(z8,  z9,  z10, z11);
        zl[ 3][tid] = make_float4(z12, z13, z14, z15);
        zl[ 4][tid] = make_float4(z16, z17, z18, z19);
        zl[ 5][tid] = make_float4(z20, z21, z22, z23);
        zl[ 6][tid] = make_float4(z24, z25, z26, z27);
        zl[ 7][tid] = make_float4(z28, z29, z30, z31);
        zl[ 8][tid] = make_float4(z32, z33, z34, z35);
        zl[ 9][tid] = make_float4(z36, z37, z38, z39);
        zl[10][tid] = make_float4(z40, z41, z42, z43);
        zl[11][tid] = make_float4(z44, z45, z46, z47);
        zl[12][tid] = make_float4(z48, z49, z50, z51);
        zl[13][tid] = make_float4(z52, z53, z54, z55);
        zl[14][tid] = make_float4(z56, z57, z58, z59);
        zl[15][tid] = make_float4(z60, z61, z62, z63);
    }

    // --- my two codes' w into registers (one-time; 32 x float4) ---
    const int cbase = seg * 512 + wid * 128;          // wave's code base
    const int cA = cbase + lane;
    const int cB = cA + 64;
    float4 wa[16], wb[16];
    {
        const float4* wpa = (const float4*)(cb + ((size_t)cA << 6));
        const float4* wpb = (const float4*)(cb + ((size_t)cB << 6));
#pragma unroll
        for (int kk = 0; kk < 16; ++kk) { wa[kk] = wpa[kk]; wb[kk] = wpb[kk]; }
    }
    WSQ_OF(wa, wsqA)
    WSQ_OF(wb, wsqB)
    __syncthreads();

    // --- pipelined row loop: FMA(i) || REDUCE(i-1) ---
    float cd0, cd1, cd2, cd3;
    bool  ct0, ct1, ct2, ct3;
    FMA4BLOCK(0, cd0, cd1, cd2, cd3, ct0, ct1, ct2, ct3)
#pragma unroll 1
    for (int r = 4; r < 256; r += 4) {
        const float pd0 = cd0, pd1 = cd1, pd2 = cd2, pd3 = cd3;
        const bool  pt0 = ct0, pt1 = ct1, pt2 = ct2, pt3 = ct3;
        FMA4BLOCK(r, cd0, cd1, cd2, cd3, ct0, ct1, ct2, ct3)
        REDUCE4(r - 4, pd0, pd1, pd2, pd3, pt0, pt1, pt2, pt3)
    }
    REDUCE4(252, cd0, cd1, cd2, cd3, ct0, ct1, ct2, ct3)
    __syncthreads();

    // --- combine the block's 4 waves (ascending wid == ascending codes) ---
    {
        float2 best = res[0][tid];
#pragma unroll
        for (int w = 1; w < 4; ++w) {
            const float2 p = res[w][tid];
            if (p.x < best.x) best = p;   // strict < keeps lower codes
        }
        pairs[seg * NROWS + row0 + tid] = best;
    }
}

__global__ void vq_argmin_kernel(const float2* __restrict__ pairs,
                                 float* __restrict__ codes) {
    int row = blockIdx.x * blockDim.x + threadIdx.x;
    float2 best = pairs[row];
#pragma unroll
    for (int s = 1; s < SEGS; ++s) {
        float2 p = pairs[s * NROWS + row];
        if (p.x < best.x) best = p;  // ascending seg order, strict <
    }
    codes[row] = best.y;
}

// One float4 (4 consecutive t) per thread; per-block double partial to ws
// (no global atomics -> deterministic, no serialization).
__global__ void vq_epilogue_kernel(const float* __restrict__ z,
                                   const float* __restrict__ cb,
                                   const float* __restrict__ codes,
                                   float* __restrict__ out,
                                   double* __restrict__ partials) {
    const int q = blockIdx.x * 256 + threadIdx.x;  // quad index, 0..1048575
    const int i = q << 2;                          // element index
    const int t = i & (T_DIM - 1);                 // multiple of 4
    const int bd = i >> 13;
    const int d = bd & (D_DIM - 1);                // uniform within a wave
    const int b = bd >> 6;
    const int row = (b << 13) | t;

    float4 cr = *(const float4*)(codes + row);     // 4 consecutive codes
    float4 zv = *(const float4*)(z + i);
    float w0 = cb[((int)cr.x << 6) + d];           // gathers, 256 KiB table
    float w1 = cb[((int)cr.y << 6) + d];
    float w2 = cb[((int)cr.z << 6) + d];
    float w3 = cb[((int)cr.w << 6) + d];

    float4 df = make_float4(w0 - zv.x, w1 - zv.y, w2 - zv.z, w3 - zv.w);
    float4 o = make_float4(zv.x + df.x, zv.y + df.y, zv.z + df.z, zv.w + df.w);
    *(float4*)(out + i) = o;                       // z + (z_q - z), ref order

    double v = (double)df.x * df.x + (double)df.y * df.y +
               (double)df.z * df.z + (double)df.w * df.w;
#pragma unroll
    for (int o2 = 32; o2 > 0; o2 >>= 1) v += __shfl_down(v, o2, 64);

    __shared__ double red[4];
    if ((threadIdx.x & 63) == 0) red[threadIdx.x >> 6] = v;
    __syncthreads();
    if (threadIdx.x == 0)
        partials[blockIdx.x] = ((red[0] + red[1]) + (red[2] + red[3]));
}

__global__ void vq_loss_kernel(const double* __restrict__ partials,
                               float* __restrict__ out_loss) {
    double s = 0.0;
    for (int i = threadIdx.x; i < EPI_BLOCKS; i += 256) s += partials[i];
#pragma unroll
    for (int o = 32; o > 0; o >>= 1) s += __shfl_down(s, o, 64);
    __shared__ double red[4];
    if ((threadIdx.x & 63) == 0) red[threadIdx.x >> 6] = s;
    __syncthreads();
    if (threadIdx.x == 0) {
        double tot = (red[0] + red[1]) + (red[2] + red[3]);
        // vq_loss = codebook_loss + 0.25*commitment_loss = 1.25*mean(diff^2)
        out_loss[0] = (float)(1.25 * tot / (double)NELEM);
    }
}

extern "C" void kernel_launch(void* const* d_in, const int* in_sizes, int n_in,
                              void* d_out, int out_size, void* d_ws, size_t ws_size,
                              hipStream_t stream) {
    const float* z  = (const float*)d_in[0];   // 4194304
    const float* cb = (const float*)d_in[1];   // 65536

    float* out      = (float*)d_out;
    float* out_loss = out + NELEM;             // index 4194304
    float* codes    = out + NELEM + 1;         // 65536 floats

    char* ws    = (char*)d_ws;
    double* partials = (double*)(ws);                  // 32 KiB (4096 doubles)
    float2* pairs = (float2*)(ws + 32768);             // 1 MiB (2 segs)

    dim3 grid1(NROWS / 256, SEGS);
    vq_dist_kernel<<<grid1, 256, 0, stream>>>(z, cb, pairs);

    vq_argmin_kernel<<<NROWS / 256, 256, 0, stream>>>(pairs, codes);

    vq_epilogue_kernel<<<EPI_BLOCKS, 256, 0, stream>>>(z, cb, codes, out, partials);

    vq_loss_kernel<<<1, 256, 0, stream>>>(partials, out_loss);
}

// Round 10
// 223.825 us; speedup vs baseline: 7.7591x; 7.7591x over previous
//
#include <hip/hip_runtime.h>

// VectorQuantizer: z (8,64,8192) f32, codebook (1024,64) f32
// Outputs (concatenated f32): z_q_st [4194304], vq_loss [1], codes [65536]
//
// codes must match numpy fp32 argmin BIT-EXACTLY -> replicate numpy op order:
//   zsq/wsq: pairwise_sum n=64 (8 serial column accumulators, rounded squares)
//   dot:     single serial FMA chain over k ascending (BLAS sgemm order)
//   dist:    fl(fl(zsq - fl(2*dot)) + wsq), argmin = first occurrence of min.
//
// Evidence ledger:
//   R6-R9: row-per-thread, w via s_load: 190us invariant (SMEM chunk drains).
//   R11: w per-lane VMEM: 500us (64x L1 amplification).
//   R12: transpose (lanes own 2 codes, w in regs, z broadcast LDS): 209us.
//   R13: batch 4 rows/iter: 175us, VALUBusy 56.6%. BEST core.
//   R14: software-pipelined reduction: 1667us -- duplicated FMA macro +
//     carried state spilled wa/wb to scratch (FETCH 5.2GB). REVERTED.
//   R13 LDS arithmetic: 8.4M broadcast b128 (~8-12cy each, per-CU pipe) +
//     3.1M bpermute ~= 136us of LDS-pipe vs 54.6us VALU -> the R13 core is
//     LDS-THROUGHPUT-bound. Fewer LDS instr needs 4 codes/lane = 256 w regs
//     (spills). So this round harvests the non-dist 66us instead.
// R15 (this round): FUSE all phases into one kernel. SEGS=1: 512-thread
//   block (8 waves x 128 codes = all 1024), one 256-row tile per block ->
//   grid = 256 blocks = 256 CUs exactly. Block knows each row's final code
//   -> argmin/epilogue/loss fold in; z already in LDS (exact bits) for
//   z_q_st + loss; z staged ONCE (was twice). Core loop = R13 body verbatim.
//   Predict: total 241 -> 195-210 (dist_fused 185-195); FETCH ~halves;
//   VGPR ~110. Falsifier: total >=235 -> fusion overhead; revert split and
//   attack LDS floor via SGPR-z row-per-lane structure.

#define T_DIM 8192
#define D_DIM 64
#define C_DIM 1024
#define B_DIM 8
#define NROWS (B_DIM * T_DIM)           // 65536 vectors
#define NELEM (B_DIM * D_DIM * T_DIM)   // 4194304 elements
#define NBLKS (NROWS / 256)             // 256 fused blocks

#define R64(M) M(0) M(1) M(2) M(3) M(4) M(5) M(6) M(7) \
  M(8) M(9) M(10) M(11) M(12) M(13) M(14) M(15) \
  M(16) M(17) M(18) M(19) M(20) M(21) M(22) M(23) \
  M(24) M(25) M(26) M(27) M(28) M(29) M(30) M(31) \
  M(32) M(33) M(34) M(35) M(36) M(37) M(38) M(39) \
  M(40) M(41) M(42) M(43) M(44) M(45) M(46) M(47) \
  M(48) M(49) M(50) M(51) M(52) M(53) M(54) M(55) \
  M(56) M(57) M(58) M(59) M(60) M(61) M(62) M(63)

#define SQ_(x) __fmul_rn(x, x)
#define AD_(a, b) __fadd_rn(a, b)

// numpy pairwise_sum of 64 pre-rounded squares of scalars p0..p63 -> dst.
#define PAIRWISE64(p, dst) \
  float pr0 = SQ_(p##0);  pr0 = AD_(pr0, SQ_(p##8));  pr0 = AD_(pr0, SQ_(p##16)); pr0 = AD_(pr0, SQ_(p##24)); pr0 = AD_(pr0, SQ_(p##32)); pr0 = AD_(pr0, SQ_(p##40)); pr0 = AD_(pr0, SQ_(p##48)); pr0 = AD_(pr0, SQ_(p##56)); \
  float pr1 = SQ_(p##1);  pr1 = AD_(pr1, SQ_(p##9));  pr1 = AD_(pr1, SQ_(p##17)); pr1 = AD_(pr1, SQ_(p##25)); pr1 = AD_(pr1, SQ_(p##33)); pr1 = AD_(pr1, SQ_(p##41)); pr1 = AD_(pr1, SQ_(p##49)); pr1 = AD_(pr1, SQ_(p##57)); \
  float pr2 = SQ_(p##2);  pr2 = AD_(pr2, SQ_(p##10)); pr2 = AD_(pr2, SQ_(p##18)); pr2 = AD_(pr2, SQ_(p##26)); pr2 = AD_(pr2, SQ_(p##34)); pr2 = AD_(pr2, SQ_(p##42)); pr2 = AD_(pr2, SQ_(p##50)); pr2 = AD_(pr2, SQ_(p##58)); \
  float pr3 = SQ_(p##3);  pr3 = AD_(pr3, SQ_(p##11)); pr3 = AD_(pr3, SQ_(p##19)); pr3 = AD_(pr3, SQ_(p##27)); pr3 = AD_(pr3, SQ_(p##35)); pr3 = AD_(pr3, SQ_(p##43)); pr3 = AD_(pr3, SQ_(p##51)); pr3 = AD_(pr3, SQ_(p##59)); \
  float pr4 = SQ_(p##4);  pr4 = AD_(pr4, SQ_(p##12)); pr4 = AD_(pr4, SQ_(p##20)); pr4 = AD_(pr4, SQ_(p##28)); pr4 = AD_(pr4, SQ_(p##36)); pr4 = AD_(pr4, SQ_(p##44)); pr4 = AD_(pr4, SQ_(p##52)); pr4 = AD_(pr4, SQ_(p##60)); \
  float pr5 = SQ_(p##5);  pr5 = AD_(pr5, SQ_(p##13)); pr5 = AD_(pr5, SQ_(p##21)); pr5 = AD_(pr5, SQ_(p##29)); pr5 = AD_(pr5, SQ_(p##37)); pr5 = AD_(pr5, SQ_(p##45)); pr5 = AD_(pr5, SQ_(p##53)); pr5 = AD_(pr5, SQ_(p##61)); \
  float pr6 = SQ_(p##6);  pr6 = AD_(pr6, SQ_(p##14)); pr6 = AD_(pr6, SQ_(p##22)); pr6 = AD_(pr6, SQ_(p##30)); pr6 = AD_(pr6, SQ_(p##38)); pr6 = AD_(pr6, SQ_(p##46)); pr6 = AD_(pr6, SQ_(p##54)); pr6 = AD_(pr6, SQ_(p##62)); \
  float pr7 = SQ_(p##7);  pr7 = AD_(pr7, SQ_(p##15)); pr7 = AD_(pr7, SQ_(p##23)); pr7 = AD_(pr7, SQ_(p##31)); pr7 = AD_(pr7, SQ_(p##39)); pr7 = AD_(pr7, SQ_(p##47)); pr7 = AD_(pr7, SQ_(p##55)); pr7 = AD_(pr7, SQ_(p##63)); \
  float dst = AD_(AD_(AD_(pr0, pr1), AD_(pr2, pr3)), AD_(AD_(pr4, pr5), AD_(pr6, pr7)));

// Same pairwise order, sourced from a float4[16] register array.
#define WSQ_OF(arr, dst) float dst; { \
  float c0 = SQ_(arr[0].x); c0=AD_(c0,SQ_(arr[2].x)); c0=AD_(c0,SQ_(arr[4].x)); c0=AD_(c0,SQ_(arr[6].x)); c0=AD_(c0,SQ_(arr[8].x)); c0=AD_(c0,SQ_(arr[10].x)); c0=AD_(c0,SQ_(arr[12].x)); c0=AD_(c0,SQ_(arr[14].x)); \
  float c1 = SQ_(arr[0].y); c1=AD_(c1,SQ_(arr[2].y)); c1=AD_(c1,SQ_(arr[4].y)); c1=AD_(c1,SQ_(arr[6].y)); c1=AD_(c1,SQ_(arr[8].y)); c1=AD_(c1,SQ_(arr[10].y)); c1=AD_(c1,SQ_(arr[12].y)); c1=AD_(c1,SQ_(arr[14].y)); \
  float c2 = SQ_(arr[0].z); c2=AD_(c2,SQ_(arr[2].z)); c2=AD_(c2,SQ_(arr[4].z)); c2=AD_(c2,SQ_(arr[6].z)); c2=AD_(c2,SQ_(arr[8].z)); c2=AD_(c2,SQ_(arr[10].z)); c2=AD_(c2,SQ_(arr[12].z)); c2=AD_(c2,SQ_(arr[14].z)); \
  float c3 = SQ_(arr[0].w); c3=AD_(c3,SQ_(arr[2].w)); c3=AD_(c3,SQ_(arr[4].w)); c3=AD_(c3,SQ_(arr[6].w)); c3=AD_(c3,SQ_(arr[8].w)); c3=AD_(c3,SQ_(arr[10].w)); c3=AD_(c3,SQ_(arr[12].w)); c3=AD_(c3,SQ_(arr[14].w)); \
  float c4 = SQ_(arr[1].x); c4=AD_(c4,SQ_(arr[3].x)); c4=AD_(c4,SQ_(arr[5].x)); c4=AD_(c4,SQ_(arr[7].x)); c4=AD_(c4,SQ_(arr[9].x)); c4=AD_(c4,SQ_(arr[11].x)); c4=AD_(c4,SQ_(arr[13].x)); c4=AD_(c4,SQ_(arr[15].x)); \
  float c5 = SQ_(arr[1].y); c5=AD_(c5,SQ_(arr[3].y)); c5=AD_(c5,SQ_(arr[5].y)); c5=AD_(c5,SQ_(arr[7].y)); c5=AD_(c5,SQ_(arr[9].y)); c5=AD_(c5,SQ_(arr[11].y)); c5=AD_(c5,SQ_(arr[13].y)); c5=AD_(c5,SQ_(arr[15].y)); \
  float c6 = SQ_(arr[1].z); c6=AD_(c6,SQ_(arr[3].z)); c6=AD_(c6,SQ_(arr[5].z)); c6=AD_(c6,SQ_(arr[7].z)); c6=AD_(c6,SQ_(arr[9].z)); c6=AD_(c6,SQ_(arr[11].z)); c6=AD_(c6,SQ_(arr[13].z)); c6=AD_(c6,SQ_(arr[15].z)); \
  float c7 = SQ_(arr[1].w); c7=AD_(c7,SQ_(arr[3].w)); c7=AD_(c7,SQ_(arr[5].w)); c7=AD_(c7,SQ_(arr[7].w)); c7=AD_(c7,SQ_(arr[9].w)); c7=AD_(c7,SQ_(arr[11].w)); c7=AD_(c7,SQ_(arr[13].w)); c7=AD_(c7,SQ_(arr[15].w)); \
  dst = AD_(AD_(AD_(c0, c1), AD_(c2, c3)), AD_(AD_(c4, c5), AD_(c6, c7))); }

// Fused kernel: 512 threads = 8 waves; each wave owns 128 codes
// (cbase=wid*128; lane -> cbase+lane, cbase+64+lane; w in regs). 256-row
// z tile in LDS (broadcast reads). R13 row loop (4 rows/iter). Then
// in-block combine -> codes, fused epilogue (z_q_st from LDS z + cb gather),
// per-block double loss partial.
__global__ __launch_bounds__(512, 2)
void vq_fused_kernel(const float* __restrict__ z,
                     const float* __restrict__ cb,
                     float* __restrict__ out,
                     float* __restrict__ codes,
                     double* __restrict__ partials) {
    const int tid  = threadIdx.x;                     // 0..511
    const int wid  = tid >> 6;                        // 0..7
    const int lane = tid & 63;
    const int row0 = blockIdx.x * 256;                // tile base (same b)
    const int b    = row0 >> 13;                      // 8192 % 256 == 0
    const int t0   = row0 & (T_DIM - 1);

    __shared__ float4 zl[16][256];                    // 64 KiB  [kchunk][row]
    __shared__ float  zsql[256];                      // 1 KiB
    __shared__ float2 res[8][256];                    // 16 KiB  [wave][row]
    __shared__ int    codesl[256];                    // 1 KiB

    // --- stage z tile: threads 0..255 handle row row0+tid (coalesced) ---
    if (tid < 256) {
        const float* zp = z + (size_t)b * (D_DIM * T_DIM) + (t0 + tid);
#define LOADZ(k) float z##k = zp[(size_t)k * T_DIM];
        R64(LOADZ)
#undef LOADZ
        PAIRWISE64(z, zsq)
        zsql[tid] = zsq;
        zl[ 0][tid] = make_float4(z0,  z1,  z2,  z3);
        zl[ 1][tid] = make_float4(z4,  z5,  z6,  z7);
        zl[ 2][tid] = make_float4(z8,  z9,  z10, z11);
        zl[ 3][tid] = make_float4(z12, z13, z14, z15);
        zl[ 4][tid] = make_float4(z16, z17, z18, z19);
        zl[ 5][tid] = make_float4(z20, z21, z22, z23);
        zl[ 6][tid] = make_float4(z24, z25, z26, z27);
        zl[ 7][tid] = make_float4(z28, z29, z30, z31);
        zl[ 8][tid] = make_float4(z32, z33, z34, z35);
        zl[ 9][tid] = make_float4(z36, z37, z38, z39);
        zl[10][tid] = make_float4(z40, z41, z42, z43);
        zl[11][tid] = make_float4(z44, z45, z46, z47);
        zl[12][tid] = make_float4(z48, z49, z50, z51);
        zl[13][tid] = make_float4(z52, z53, z54, z55);
        zl[14][tid] = make_float4(z56, z57, z58, z59);
        zl[15][tid] = make_float4(z60, z61, z62, z63);
    }

    // --- my two codes' w into registers (one-time; 32 x float4) ---
    const int cbase = wid * 128;                      // wave's code base
    const int cA = cbase + lane;
    const int cB = cA + 64;
    float4 wa[16], wb[16];
    {
        const float4* wpa = (const float4*)(cb + ((size_t)cA << 6));
        const float4* wpb = (const float4*)(cb + ((size_t)cB << 6));
#pragma unroll
        for (int kk = 0; kk < 16; ++kk) { wa[kk] = wpa[kk]; wb[kk] = wpb[kk]; }
    }
    WSQ_OF(wa, wsqA)
    WSQ_OF(wb, wsqB)
    __syncthreads();

    // --- R13 row loop: 4 rows/iter, 8 FMA chains, 4 interleaved shfl-min
    //     chains, ballot first-min per row ---
#pragma unroll 1
    for (int r = 0; r < 256; r += 4) {
        float aA0 = 0.f, aA1 = 0.f, aA2 = 0.f, aA3 = 0.f;
        float aB0 = 0.f, aB1 = 0.f, aB2 = 0.f, aB3 = 0.f;
#pragma unroll
        for (int kk = 0; kk < 16; ++kk) {
            const float4 zc0 = zl[kk][r + 0];   // broadcast reads
            const float4 zc1 = zl[kk][r + 1];
            const float4 zc2 = zl[kk][r + 2];
            const float4 zc3 = zl[kk][r + 3];
            const float4 WA = wa[kk];
            const float4 WB = wb[kk];
            aA0 = fmaf(zc0.x, WA.x, aA0); aA0 = fmaf(zc0.y, WA.y, aA0);
            aA0 = fmaf(zc0.z, WA.z, aA0); aA0 = fmaf(zc0.w, WA.w, aA0);
            aB0 = fmaf(zc0.x, WB.x, aB0); aB0 = fmaf(zc0.y, WB.y, aB0);
            aB0 = fmaf(zc0.z, WB.z, aB0); aB0 = fmaf(zc0.w, WB.w, aB0);
            aA1 = fmaf(zc1.x, WA.x, aA1); aA1 = fmaf(zc1.y, WA.y, aA1);
            aA1 = fmaf(zc1.z, WA.z, aA1); aA1 = fmaf(zc1.w, WA.w, aA1);
            aB1 = fmaf(zc1.x, WB.x, aB1); aB1 = fmaf(zc1.y, WB.y, aB1);
            aB1 = fmaf(zc1.z, WB.z, aB1); aB1 = fmaf(zc1.w, WB.w, aB1);
            aA2 = fmaf(zc2.x, WA.x, aA2); aA2 = fmaf(zc2.y, WA.y, aA2);
            aA2 = fmaf(zc2.z, WA.z, aA2); aA2 = fmaf(zc2.w, WA.w, aA2);
            aB2 = fmaf(zc2.x, WB.x, aB2); aB2 = fmaf(zc2.y, WB.y, aB2);
            aB2 = fmaf(zc2.z, WB.z, aB2); aB2 = fmaf(zc2.w, WB.w, aB2);
            aA3 = fmaf(zc3.x, WA.x, aA3); aA3 = fmaf(zc3.y, WA.y, aA3);
            aA3 = fmaf(zc3.z, WA.z, aA3); aA3 = fmaf(zc3.w, WA.w, aA3);
            aB3 = fmaf(zc3.x, WB.x, aB3); aB3 = fmaf(zc3.y, WB.y, aB3);
            aB3 = fmaf(zc3.z, WB.z, aB3); aB3 = fmaf(zc3.w, WB.w, aB3);
        }
        const float zr0 = zsql[r + 0];
        const float zr1 = zsql[r + 1];
        const float zr2 = zsql[r + 2];
        const float zr3 = zsql[r + 3];
        // d = (zsq - 2*dot) + wsq, each op individually rounded
        const float dA0 = __fadd_rn(__fsub_rn(zr0, __fmul_rn(2.0f, aA0)), wsqA);
        const float dB0 = __fadd_rn(__fsub_rn(zr0, __fmul_rn(2.0f, aB0)), wsqB);
        const float dA1 = __fadd_rn(__fsub_rn(zr1, __fmul_rn(2.0f, aA1)), wsqA);
        const float dB1 = __fadd_rn(__fsub_rn(zr1, __fmul_rn(2.0f, aB1)), wsqB);
        const float dA2 = __fadd_rn(__fsub_rn(zr2, __fmul_rn(2.0f, aA2)), wsqA);
        const float dB2 = __fadd_rn(__fsub_rn(zr2, __fmul_rn(2.0f, aB2)), wsqB);
        const float dA3 = __fadd_rn(__fsub_rn(zr3, __fmul_rn(2.0f, aA3)), wsqA);
        const float dB3 = __fadd_rn(__fsub_rn(zr3, __fmul_rn(2.0f, aB3)), wsqB);
        // pair pre-min (A wins ties: lower code)
        const bool tB0 = (dB0 < dA0); const float d0 = tB0 ? dB0 : dA0;
        const bool tB1 = (dB1 < dA1); const float d1 = tB1 ? dB1 : dA1;
        const bool tB2 = (dB2 < dA2); const float d2 = tB2 ? dB2 : dA2;
        const bool tB3 = (dB3 < dA3); const float d3 = tB3 ? dB3 : dA3;
        // 4 independent wave-min chains, interleaved -> pipelined bpermutes
        float m0 = d0, m1 = d1, m2 = d2, m3 = d3;
#pragma unroll
        for (int off = 32; off > 0; off >>= 1) {
            m0 = fminf(m0, __shfl_xor(m0, off, 64));
            m1 = fminf(m1, __shfl_xor(m1, off, 64));
            m2 = fminf(m2, __shfl_xor(m2, off, 64));
            m3 = fminf(m3, __shfl_xor(m3, off, 64));
        }
#define ARGMIN_J(mj, dj, tBj, outIdx) { \
        const unsigned long long mskA = __ballot((!tBj) && (dj == mj)); \
        const unsigned long long mskB = __ballot(tBj && (dj == mj)); \
        int code; \
        if (mskA) code = cbase + (__ffsll((long long)mskA) - 1); \
        else      code = cbase + 64 + (__ffsll((long long)mskB) - 1); \
        if (lane == 0) res[wid][outIdx] = make_float2(mj, (float)code); }
        ARGMIN_J(m0, d0, tB0, r + 0)
        ARGMIN_J(m1, d1, tB1, r + 1)
        ARGMIN_J(m2, d2, tB2, r + 2)
        ARGMIN_J(m3, d3, tB3, r + 3)
#undef ARGMIN_J
    }
    __syncthreads();

    // --- combine 8 waves (ascending wid == ascending code blocks) ---
    if (tid < 256) {
        float2 best = res[0][tid];
#pragma unroll
        for (int w = 1; w < 8; ++w) {
            const float2 p = res[w][tid];
            if (p.x < best.x) best = p;   // strict < keeps lower codes
        }
        codes[row0 + tid] = best.y;
        codesl[tid] = (int)best.y;
    }
    __syncthreads();

    // --- fused epilogue: out[b,d,t] = fl(z + fl(w - z)); loss partial ---
    // thread -> (d-pair, t): hi = tid>>8 (0/1), tl = tid&255.
    // wave lanes share d, consecutive t -> coalesced 256B stores.
    const int hi = tid >> 8;
    const int tl = tid & 255;
    double lsum = 0.0;
    float* outb = out + (size_t)b * (D_DIM * T_DIM);
#pragma unroll 1
    for (int it = 0; it < 32; ++it) {
        const int d = (it << 1) + hi;                 // 0..63, wave-uniform
        const int code = codesl[tl];
        const float4 zq4 = zl[d >> 2][tl];
        const float zv = (d & 3) == 0 ? zq4.x : (d & 3) == 1 ? zq4.y
                       : (d & 3) == 2 ? zq4.z : zq4.w;
        const float wv = cb[(code << 6) + d];         // gather, L2-resident
        const float df = __fsub_rn(wv, zv);           // fl(z_q - z)
        outb[(size_t)d * T_DIM + (t0 + tl)] = __fadd_rn(zv, df);
        lsum += (double)df * (double)df;
    }
    // wave reduce (double) then block reduce via LDS
#pragma unroll
    for (int o2 = 32; o2 > 0; o2 >>= 1) lsum += __shfl_down(lsum, o2, 64);
    __shared__ double redd[8];
    if (lane == 0) redd[wid] = lsum;
    __syncthreads();
    if (tid == 0) {
        double t4 = ((redd[0] + redd[1]) + (redd[2] + redd[3]))
                  + ((redd[4] + redd[5]) + (redd[6] + redd[7]));
        partials[blockIdx.x] = t4;
    }
}

__global__ void vq_loss_kernel(const double* __restrict__ partials,
                               float* __restrict__ out_loss) {
    double s = 0.0;
    for (int i = threadIdx.x; i < NBLKS; i += 256) s += partials[i];
#pragma unroll
    for (int o = 32; o > 0; o >>= 1) s += __shfl_down(s, o, 64);
    __shared__ double red[4];
    if ((threadIdx.x & 63) == 0) red[threadIdx.x >> 6] = s;
    __syncthreads();
    if (threadIdx.x == 0) {
        double tot = (red[0] + red[1]) + (red[2] + red[3]);
        // vq_loss = codebook_loss + 0.25*commitment_loss = 1.25*mean(diff^2)
        out_loss[0] = (float)(1.25 * tot / (double)NELEM);
    }
}

extern "C" void kernel_launch(void* const* d_in, const int* in_sizes, int n_in,
                              void* d_out, int out_size, void* d_ws, size_t ws_size,
                              hipStream_t stream) {
    const float* z  = (const float*)d_in[0];   // 4194304
    const float* cb = (const float*)d_in[1];   // 65536

    float* out      = (float*)d_out;
    float* out_loss = out + NELEM;             // index 4194304
    float* codes    = out + NELEM + 1;         // 65536 floats

    double* partials = (double*)d_ws;          // 2 KiB (256 doubles)

    vq_fused_kernel<<<NBLKS, 512, 0, stream>>>(z, cb, out, codes, partials);
    vq_loss_kernel<<<1, 256, 0, stream>>>(partials, out_loss);
}